// Round 1
// 1563.413 us; speedup vs baseline: 1.1656x; 1.1656x over previous
//
#include <hip/hip_runtime.h>
#include <stdint.h>
#include <stddef.h>

#define AS1 __attribute__((address_space(1)))
#define AS3 __attribute__((address_space(3)))

typedef __attribute__((ext_vector_type(8))) short bf16x8;   // 8 bf16 = 4 VGPRs
typedef __attribute__((ext_vector_type(4))) float f32x4;

static constexpr int S = 4096, D = 4096, HID = 11008;

__device__ __forceinline__ unsigned short f2bf(float f) {
  unsigned u = __float_as_uint(f);
  u += 0x7FFFu + ((u >> 16) & 1u);       // RNE
  return (unsigned short)(u >> 16);
}

// async global->LDS, 16B per lane; lds dest is wave-uniform base + lane*16
__device__ __forceinline__ void async16(const void* gsrc, void* ldst) {
  __builtin_amdgcn_global_load_lds((AS1 void*)const_cast<void*>(gsrc),
                                   (AS3 void*)ldst, 16, 0, 0);
}

// ---------------- fp32 -> bf16 elementwise (x) ----------------
__global__ __launch_bounds__(256) void k_cvt_bf16(const float* __restrict__ src,
                                                  unsigned short* __restrict__ dst) {
  int i = blockIdx.x * 256 + threadIdx.x;          // 8 elems / thread
  const float4* s = (const float4*)src;
  float4 a = s[2 * i];
  float4 b = s[2 * i + 1];
  union { unsigned short h[8]; uint4 v; } r;
  r.h[0] = f2bf(a.x); r.h[1] = f2bf(a.y); r.h[2] = f2bf(a.z); r.h[3] = f2bf(a.w);
  r.h[4] = f2bf(b.x); r.h[5] = f2bf(b.y); r.h[6] = f2bf(b.z); r.h[7] = f2bf(b.w);
  ((uint4*)dst)[i] = r.v;
}

// ------------- fp32 [R][C] -> bf16 [C][R] transpose+convert -------------
__global__ __launch_bounds__(256) void k_tcvt(const float* __restrict__ src,
                                              unsigned short* __restrict__ dst,
                                              int R, int C) {
  __shared__ float tile[64][65];                    // +1 pad: conflict-free transpose
  const int tid = threadIdx.x;
  const int c0 = blockIdx.x * 64;
  const int r0 = blockIdx.y * 64;
#pragma unroll
  for (int it = 0; it < 16; ++it) {
    int f = it * 256 + tid;
    int r = f >> 6, c = f & 63;
    tile[r][c] = src[(size_t)(r0 + r) * C + (c0 + c)];
  }
  __syncthreads();
#pragma unroll
  for (int it = 0; it < 8; ++it) {
    int f = it * 512 + tid * 2;
    int cc = f >> 6, rr = f & 63;
    unsigned p0 = f2bf(tile[rr][cc]);
    unsigned p1 = f2bf(tile[rr + 1][cc]);
    *(unsigned*)(dst + (size_t)(c0 + cc) * R + (r0 + rr)) = p0 | (p1 << 16);
  }
}

// =====================================================================
// Pipelined GEMMs: BK=32, 4 LDS slots, stage 3 tiles ahead, counted vmcnt.
// LDS logical layout (per slot, per matrix tile [ROWS][32] bf16):
//   physical row p (128B = 8x 16B slots) holds logical rows {2p, 2p+1};
//   16B slot s of phys row p holds logical (r = 2p + (u>>2), kchunk = u&3)
//   where u = s ^ (p&7).  ds_read_b128 of logical (r, lq) is then at
//   byte (r>>1)*128 + ((((r&1)<<2)|lq) ^ ((r>>1)&7))*16  -> 2-way banks (free).
//   global_load_lds writes linearly; the SOURCE address is pre-swizzled.
// =====================================================================

// ------------- GEMM1 fused: gate=x@W1, up=x@W3, h=silu(gate)*up -------------
// A: [S][D] bf16; B1,B3: [HID][D] bf16 (W^T); Hout: [S][HID] bf16
// Block 512 thr (8 waves 2Mx4N), tile BM=256 x BN=128 (both outputs), BK=32.
__global__ __launch_bounds__(512, 2) void gemm_gateup(
    const unsigned short* __restrict__ A,
    const unsigned short* __restrict__ B1,
    const unsigned short* __restrict__ B3,
    unsigned short* __restrict__ Hout) {
  __shared__ __align__(16) unsigned short sL[65536];   // 4 slots x 32KB
  constexpr int NT = D / 32;                           // 128
  const int tid = threadIdx.x;
  const int wave = tid >> 6, lane = tid & 63;
  const int wy = wave >> 2, wx = wave & 3;             // 2M x 4N
  const int lm = lane & 15, lq = lane >> 4;

  // bijective XCD swizzle (nwg % 8 == 0)
  const int q = (int)gridDim.x >> 3;
  const int wg = (blockIdx.x & 7) * q + (blockIdx.x >> 3);
  const int m0 = (wg / (HID / 128)) * 256;
  const int n0 = (wg % (HID / 128)) * 128;

  // LDS read bases (elem units; phys row = 64 elems)
  const int h = lm >> 1;
  const int sw = ((((lm & 1) << 2) | lq) ^ h);
  const int aBase  = (wy * 64 + h) * 64 + sw * 8;          // A region [0,8192)
  const int b1Base = 8192  + (wx * 16 + h) * 64 + sw * 8;  // B1 [8192,12288)
  const int b3Base = 12288 + (wx * 16 + h) * 64 + sw * 8;  // B3 [12288,16384)

  // staging source mapping (inverse swizzle): chunk ci=tid (and +512 for A)
  const int p0 = tid >> 3, s0 = tid & 7;
  const int u0 = s0 ^ (p0 & 7);
  const int rr0 = 2 * p0 + (u0 >> 2);          // 0..127
  const int kc0 = (u0 & 3) * 8;

  const unsigned short* pA0 = A  + (size_t)(m0 + rr0) * D + kc0;
  const unsigned short* pA1 = pA0 + (size_t)128 * D;
  const unsigned short* pB1 = B1 + (size_t)(n0 + rr0) * D + kc0;
  const unsigned short* pB3 = B3 + (size_t)(n0 + rr0) * D + kc0;

  f32x4 zero = {0.f, 0.f, 0.f, 0.f};
  f32x4 accg[8][2], accu[8][2];
#pragma unroll
  for (int i = 0; i < 8; ++i)
#pragma unroll
    for (int j = 0; j < 2; ++j) { accg[i][j] = zero; accu[i][j] = zero; }

  // prologue: stage tiles 0..2 (per-tile order must match loop: A0,A1,B1,B3)
#pragma unroll
  for (int x = 0; x < 3; ++x) {
    const int nso = x * 16384;
    async16(pA0, sL + nso + wave * 512);
    async16(pA1, sL + nso + 4096 + wave * 512);
    async16(pB1, sL + nso + 8192 + wave * 512);
    async16(pB3, sL + nso + 12288 + wave * 512);
    pA0 += 32; pA1 += 32; pB1 += 32; pB3 += 32;
  }
  asm volatile("s_waitcnt vmcnt(8)" ::: "memory");   // tile 0 landed
  __builtin_amdgcn_s_barrier();

  for (int t = 0; t < NT; ++t) {
    const int so  = (t & 3) * 16384;
    const int nso = ((t + 3) & 3) * 16384;
    const bool st = (t + 3 < NT);
    bf16x8 b1f[2], b3f[2], af[4];
    // ---- phase 0: B frags + A frags 0..3, stage next A ----
#pragma unroll
    for (int j = 0; j < 2; ++j) {
      b1f[j] = *(const bf16x8*)(sL + so + b1Base + j * 512);
      b3f[j] = *(const bf16x8*)(sL + so + b3Base + j * 512);
    }
#pragma unroll
    for (int i = 0; i < 4; ++i)
      af[i] = *(const bf16x8*)(sL + so + aBase + i * 512);
    if (st) {
      async16(pA0, sL + nso + wave * 512);
      async16(pA1, sL + nso + 4096 + wave * 512);
      pA0 += 32; pA1 += 32;
    }
    __builtin_amdgcn_s_barrier();
    asm volatile("s_waitcnt lgkmcnt(0)" ::: "memory");
    __builtin_amdgcn_sched_barrier(0);
    __builtin_amdgcn_s_setprio(1);
#pragma unroll
    for (int j = 0; j < 2; ++j)
#pragma unroll
      for (int i = 0; i < 4; ++i) {
        accg[i][j] = __builtin_amdgcn_mfma_f32_16x16x32_bf16(af[i], b1f[j], accg[i][j], 0, 0, 0);
        accu[i][j] = __builtin_amdgcn_mfma_f32_16x16x32_bf16(af[i], b3f[j], accu[i][j], 0, 0, 0);
      }
    __builtin_amdgcn_s_setprio(0);
    __builtin_amdgcn_s_barrier();
    // ---- phase 1: A frags 4..7, stage next B ----
#pragma unroll
    for (int i = 0; i < 4; ++i)
      af[i] = *(const bf16x8*)(sL + so + aBase + (4 + i) * 512);
    if (st) {
      async16(pB1, sL + nso + 8192 + wave * 512);
      async16(pB3, sL + nso + 12288 + wave * 512);
      pB1 += 32; pB3 += 32;
    }
    __builtin_amdgcn_s_barrier();
    asm volatile("s_waitcnt lgkmcnt(0)" ::: "memory");
    __builtin_amdgcn_sched_barrier(0);
    __builtin_amdgcn_s_setprio(1);
#pragma unroll
    for (int j = 0; j < 2; ++j)
#pragma unroll
      for (int i = 0; i < 4; ++i) {
        accg[4 + i][j] = __builtin_amdgcn_mfma_f32_16x16x32_bf16(af[i], b1f[j], accg[4 + i][j], 0, 0, 0);
        accu[4 + i][j] = __builtin_amdgcn_mfma_f32_16x16x32_bf16(af[i], b3f[j], accu[4 + i][j], 0, 0, 0);
      }
    __builtin_amdgcn_s_setprio(0);
    // tile-end: counted drain — t+1 must be landed, keep t+2/t+3 in flight
    if (t + 3 < NT)      asm volatile("s_waitcnt vmcnt(8)" ::: "memory");
    else if (t + 2 < NT) asm volatile("s_waitcnt vmcnt(4)" ::: "memory");
    else if (t + 1 < NT) asm volatile("s_waitcnt vmcnt(0)" ::: "memory");
    __builtin_amdgcn_s_barrier();
  }

  // epilogue: h = silu(g)*u, bf16.  C/D layout: col=lane&15, row=(lane>>4)*4+r
#pragma unroll
  for (int i = 0; i < 8; ++i)
#pragma unroll
    for (int j = 0; j < 2; ++j) {
      const int col = n0 + wx * 32 + j * 16 + lm;
#pragma unroll
      for (int r = 0; r < 4; ++r) {
        const int row = m0 + wy * 128 + i * 16 + lq * 4 + r;
        float g = accg[i][j][r];
        float u = accu[i][j][r];
        float hv = (g / (1.0f + __expf(-g))) * u;
        Hout[(size_t)row * HID + col] = f2bf(hv);
      }
    }
}

// ------------- GEMM2: out = h @ W2   (A:[S][HID], B:[D][HID]=W2^T, C fp32) -------------
// Block 512 thr (8 waves 2Mx4N), tile 256x256, BK=32. Grid = 256 = 1 block/CU.
__global__ __launch_bounds__(512, 2) void gemm_out(
    const unsigned short* __restrict__ A,
    const unsigned short* __restrict__ B,
    float* __restrict__ C) {
  __shared__ __align__(16) unsigned short sL[65536];   // 4 slots x 32KB
  constexpr int NT = HID / 32;                         // 344
  const int tid = threadIdx.x;
  const int wave = tid >> 6, lane = tid & 63;
  const int wy = wave >> 2, wx = wave & 3;
  const int lm = lane & 15, lq = lane >> 4;

  const int q = (int)gridDim.x >> 3;
  const int wg = (blockIdx.x & 7) * q + (blockIdx.x >> 3);
  const int m0 = (wg >> 4) * 256;
  const int n0 = (wg & 15) * 256;

  const int h = lm >> 1;
  const int sw = ((((lm & 1) << 2) | lq) ^ h);
  const int aBase = (wy * 64 + h) * 64 + sw * 8;           // A [0,8192)
  const int bBase = 8192 + (wx * 32 + h) * 64 + sw * 8;    // B [8192,16384)

  const int p0 = tid >> 3, s0 = tid & 7;
  const int u0 = s0 ^ (p0 & 7);
  const int rr0 = 2 * p0 + (u0 >> 2);
  const int kc0 = (u0 & 3) * 8;

  const unsigned short* pA0 = A + (size_t)(m0 + rr0) * HID + kc0;
  const unsigned short* pA1 = pA0 + (size_t)128 * HID;
  const unsigned short* pB0 = B + (size_t)(n0 + rr0) * HID + kc0;
  const unsigned short* pB1 = pB0 + (size_t)128 * HID;

  f32x4 zero = {0.f, 0.f, 0.f, 0.f};
  f32x4 acc[8][4];
#pragma unroll
  for (int i = 0; i < 8; ++i)
#pragma unroll
    for (int j = 0; j < 4; ++j) acc[i][j] = zero;

#pragma unroll
  for (int x = 0; x < 3; ++x) {
    const int nso = x * 16384;
    async16(pA0, sL + nso + wave * 512);
    async16(pA1, sL + nso + 4096 + wave * 512);
    async16(pB0, sL + nso + 8192 + wave * 512);
    async16(pB1, sL + nso + 12288 + wave * 512);
    pA0 += 32; pA1 += 32; pB0 += 32; pB1 += 32;
  }
  asm volatile("s_waitcnt vmcnt(8)" ::: "memory");
  __builtin_amdgcn_s_barrier();

  for (int t = 0; t < NT; ++t) {
    const int so  = (t & 3) * 16384;
    const int nso = ((t + 3) & 3) * 16384;
    const bool st = (t + 3 < NT);
    bf16x8 bf[4], af[4];
    // ---- phase 0 ----
#pragma unroll
    for (int j = 0; j < 4; ++j)
      bf[j] = *(const bf16x8*)(sL + so + bBase + j * 512);
#pragma unroll
    for (int i = 0; i < 4; ++i)
      af[i] = *(const bf16x8*)(sL + so + aBase + i * 512);
    if (st) {
      async16(pA0, sL + nso + wave * 512);
      async16(pA1, sL + nso + 4096 + wave * 512);
      pA0 += 32; pA1 += 32;
    }
    __builtin_amdgcn_s_barrier();
    asm volatile("s_waitcnt lgkmcnt(0)" ::: "memory");
    __builtin_amdgcn_sched_barrier(0);
    __builtin_amdgcn_s_setprio(1);
#pragma unroll
    for (int j = 0; j < 4; ++j)
#pragma unroll
      for (int i = 0; i < 4; ++i)
        acc[i][j] = __builtin_amdgcn_mfma_f32_16x16x32_bf16(af[i], bf[j], acc[i][j], 0, 0, 0);
    __builtin_amdgcn_s_setprio(0);
    __builtin_amdgcn_s_barrier();
    // ---- phase 1 ----
#pragma unroll
    for (int i = 0; i < 4; ++i)
      af[i] = *(const bf16x8*)(sL + so + aBase + (4 + i) * 512);
    if (st) {
      async16(pB0, sL + nso + 8192 + wave * 512);
      async16(pB1, sL + nso + 12288 + wave * 512);
      pB0 += 32; pB1 += 32;
    }
    __builtin_amdgcn_s_barrier();
    asm volatile("s_waitcnt lgkmcnt(0)" ::: "memory");
    __builtin_amdgcn_sched_barrier(0);
    __builtin_amdgcn_s_setprio(1);
#pragma unroll
    for (int j = 0; j < 4; ++j)
#pragma unroll
      for (int i = 0; i < 4; ++i)
        acc[4 + i][j] = __builtin_amdgcn_mfma_f32_16x16x32_bf16(af[i], bf[j], acc[4 + i][j], 0, 0, 0);
    __builtin_amdgcn_s_setprio(0);
    if (t + 3 < NT)      asm volatile("s_waitcnt vmcnt(8)" ::: "memory");
    else if (t + 2 < NT) asm volatile("s_waitcnt vmcnt(4)" ::: "memory");
    else if (t + 1 < NT) asm volatile("s_waitcnt vmcnt(0)" ::: "memory");
    __builtin_amdgcn_s_barrier();
  }

#pragma unroll
  for (int i = 0; i < 8; ++i)
#pragma unroll
    for (int j = 0; j < 4; ++j) {
      const int col = n0 + wx * 64 + j * 16 + lm;
#pragma unroll
      for (int r = 0; r < 4; ++r) {
        const int row = m0 + wy * 128 + i * 16 + lq * 4 + r;
        C[(size_t)row * D + col] = acc[i][j][r];
      }
    }
}

extern "C" void kernel_launch(void* const* d_in, const int* in_sizes, int n_in,
                              void* d_out, int out_size, void* d_ws, size_t ws_size,
                              hipStream_t stream) {
  const float* x  = (const float*)d_in[0];   // [S][D]
  const float* w1 = (const float*)d_in[1];   // [D][HID]
  const float* w2 = (const float*)d_in[2];   // [HID][D]
  const float* w3 = (const float*)d_in[3];   // [D][HID]
  float* out = (float*)d_out;                // [S][D]

  char* ws = (char*)d_ws;
  // layout (bytes): xb 33,554,432 | w1t 90,177,536 | w3t 90,177,536 | h 90,177,536
  unsigned short* xb   = (unsigned short*)(ws);
  unsigned short* w1t  = (unsigned short*)(ws + (size_t)33554432);
  unsigned short* w3t  = (unsigned short*)(ws + (size_t)123731968);
  unsigned short* hbuf = (unsigned short*)(ws + (size_t)213909504);
  unsigned short* w2t  = w1t;   // W2^T reuses W1^T region after gemm_gateup

  k_cvt_bf16<<<dim3((S * D) / 8 / 256), 256, 0, stream>>>(x, xb);
  k_tcvt<<<dim3(HID / 64, D / 64), 256, 0, stream>>>(w1, w1t, D, HID);
  k_tcvt<<<dim3(HID / 64, D / 64), 256, 0, stream>>>(w3, w3t, D, HID);
  gemm_gateup<<<dim3((S / 256) * (HID / 128)), 512, 0, stream>>>(xb, w1t, w3t, hbuf);
  k_tcvt<<<dim3(D / 64, HID / 64), 256, 0, stream>>>(w2, w2t, HID, D);
  gemm_out<<<dim3((S / 256) * (D / 256)), 512, 0, stream>>>(hbuf, w2t, out);
}